// Round 8
// baseline (144.575 us; speedup 1.0000x reference)
//
#include <hip/hip_runtime.h>
#include <math.h>

#define NN 8192
#define DH 64
#define DOUT 10
#define NG 64      // number of graphs
#define NPG 128    // nodes per graph
#define NITER 5
#define CAP 192    // max edges per row (deg ~82 +- 9)
#define NCHUNK (NN * NN / 256)   // 262144 chunks of 256 floats
#define RPW 2      // rows per wave in gin_layer

typedef float f32x4 __attribute__((ext_vector_type(4)));
typedef unsigned long long u64;
typedef u64 u64x2 __attribute__((ext_vector_type(2)));

// Grid-stride streaming scan: adj -> occupancy bitmap (32 B per 256-float
// chunk). Bit layout: chunk g, word K (0..3), bit b <-> col g*256 + 4*b + K.
// ROUND 8: launched TWICE (idempotent) to measure scan time by differencing
// total dur_us against round 7 (which was identical but launched it once).
__global__ __launch_bounds__(256) void scan_bitmap(
    const float* __restrict__ adj, u64* __restrict__ bmp)
{
    const int lane = threadIdx.x & 63;
    const int gw   = (blockIdx.x * 256 + threadIdx.x) >> 6;
    const int nw   = (gridDim.x * 256) >> 6;
    #pragma unroll 4
    for (int g = gw; g < NCHUNK; g += nw) {
        f32x4 a4 = *reinterpret_cast<const f32x4*>(adj + (size_t)g * 256 + lane * 4);
        u64 m0 = __ballot(a4.x != 0.0f);
        u64 m1 = __ballot(a4.y != 0.0f);
        u64 m2 = __ballot(a4.z != 0.0f);
        u64 m3 = __ballot(a4.w != 0.0f);
        u64 msel = (lane & 2) ? ((lane & 1) ? m3 : m2)
                              : ((lane & 1) ? m1 : m0);
        if (lane < 4) bmp[(size_t)g * 4 + lane] = msel;
    }
}

// GIN layer from bitmap: one wave per row (RPW rows each).
__global__ __launch_bounds__(256) void gin_layer(
    const float* __restrict__ x, const u64* __restrict__ bmp,
    const float* __restrict__ W, const float* __restrict__ bias,
    float* __restrict__ out)
{
    __shared__ float sW[DH * DH];
    __shared__ unsigned short sJ[4][CAP];

    for (int t = threadIdx.x; t < DH * DH; t += 256) sW[t] = W[t];
    __syncthreads();

    const int wave = threadIdx.x >> 6;
    const int lane = threadIdx.x & 63;

    float wreg[DH];
    #pragma unroll
    for (int k = 0; k < DH; ++k) wreg[k] = sW[k * DH + lane];  // W column `lane`
    const float bl_ = bias[lane];

    const int wgid = blockIdx.x * 4 + wave;

    for (int rr = 0; rr < RPW; ++rr) {
        const int row = wgid * RPW + rr;
        const u64* brow = bmp + (size_t)row * (NN / 64);   // 128 words

        u64x2 wp = *reinterpret_cast<const u64x2*>(brow + 2 * lane);
        u64 w0 = wp.x, w1 = wp.y;
        int cnt = __popcll(w0) + __popcll(w1);

        int p = cnt;                      // inclusive prefix over lanes
        #pragma unroll
        for (int off = 1; off < 64; off <<= 1) {
            int t = __shfl_up(p, off);
            if (lane >= off) p += t;
        }
        int pos  = p - cnt;               // exclusive prefix
        int ctot = __shfl(p, 63);

        {   // emit edges for my two words (bit b of word widx -> column j)
            int widx = 2 * lane;
            int base0 = (widx >> 2) * 256 + (widx & 3);
            while (w0) { int b = __ffsll(w0) - 1; w0 &= w0 - 1;
                         sJ[wave][pos++] = (unsigned short)(base0 + 4 * b); }
            int widx1 = 2 * lane + 1;
            int base1 = (widx1 >> 2) * 256 + (widx1 & 3);
            while (w1) { int b = __ffsll(w1) - 1; w1 &= w1 - 1;
                         sJ[wave][pos++] = (unsigned short)(base1 + 4 * b); }
        }

        float acc = x[row * DH + lane];   // self-loop
        #pragma unroll 4
        for (int e = 0; e < ctot; ++e) {
            int j = sJ[wave][e];          // wave-uniform LDS broadcast
            acc += x[j * DH + lane];
        }

        float o = bl_;
        #pragma unroll
        for (int k = 0; k < DH; ++k)
            o = fmaf(__shfl(acc, k), wreg[k], o);
        out[row * DH + lane] = fmaxf(o, 0.0f);
    }
}

// One block (256 threads) per graph: power-iteration rs-pool + classifier + log_softmax
__global__ __launch_bounds__(256) void rspool_head(
    const float* __restrict__ h, const float* __restrict__ Wl,
    const float* __restrict__ bl, float* __restrict__ out)
{
    __shared__ float sX[NPG * 65];    // padded LD=65: conflict-free both axes
    __shared__ float sY[NPG];
    __shared__ float sVec[DH];
    __shared__ float sPart[4][DH];
    __shared__ float sPooled[DH];
    __shared__ float sO[DOUT];

    const int g = blockIdx.x;
    const int d = threadIdx.x & 63;
    const int q = threadIdx.x >> 6;

    const float* hg = h + (size_t)g * NPG * DH;
    for (int t = threadIdx.x; t < NPG * DH; t += 256)
        sX[(t >> 6) * 65 + (t & 63)] = hg[t];
    __syncthreads();

    {
        float p = 0.0f;
        for (int i = q * 32; i < q * 32 + 32; ++i) p += sX[i * 65 + d];
        sPart[q][d] = p;
    }
    __syncthreads();
    if (threadIdx.x < 64) {
        float v = sPart[0][d] + sPart[1][d] + sPart[2][d] + sPart[3][d];
        float s = v * v;
        #pragma unroll
        for (int off = 32; off > 0; off >>= 1) s += __shfl_xor(s, off);
        sVec[d] = v / (sqrtf(s) + 1e-8f);
    }
    __syncthreads();

    for (int it = 0; it < NITER; ++it) {
        if (threadIdx.x < NPG) {
            int i = threadIdx.x;
            float yy = 0.0f;
            #pragma unroll
            for (int dd = 0; dd < DH; ++dd) yy += sX[i * 65 + dd] * sVec[dd];
            sY[i] = yy;
        }
        __syncthreads();
        {
            float p = 0.0f;
            for (int i = q * 32; i < q * 32 + 32; ++i) p += sY[i] * sX[i * 65 + d];
            sPart[q][d] = p;
        }
        __syncthreads();
        if (threadIdx.x < 64) {
            float v = sPart[0][d] + sPart[1][d] + sPart[2][d] + sPart[3][d];
            float s = v * v;
            #pragma unroll
            for (int off = 32; off > 0; off >>= 1) s += __shfl_xor(s, off);
            sVec[d] = v / (sqrtf(s) + 1e-8f);
        }
        __syncthreads();
    }

    if (threadIdx.x < NPG) {
        int i = threadIdx.x;
        float yy = 0.0f;
        #pragma unroll
        for (int dd = 0; dd < DH; ++dd) yy += sX[i * 65 + dd] * sVec[dd];
        sY[i] = yy;
    }
    __syncthreads();
    if (threadIdx.x < 64) {
        float s = sY[d] * sY[d] + sY[64 + d] * sY[64 + d];
        #pragma unroll
        for (int off = 32; off > 0; off >>= 1) s += __shfl_xor(s, off);
        float sv = sqrtf(s);
        sPooled[d] = sVec[d] * sv;
    }
    __syncthreads();

    if (threadIdx.x < DOUT) {
        int c = threadIdx.x;
        float o = bl[c];
        #pragma unroll
        for (int dd = 0; dd < DH; ++dd) o += sPooled[dd] * Wl[dd * DOUT + c];
        sO[c] = o;
    }
    __syncthreads();
    if (threadIdx.x < DOUT) {
        int c = threadIdx.x;
        float mx = -INFINITY;
        #pragma unroll
        for (int j = 0; j < DOUT; ++j) mx = fmaxf(mx, sO[j]);
        float se = 0.0f;
        #pragma unroll
        for (int j = 0; j < DOUT; ++j) se += expf(sO[j] - mx);
        out[g * DOUT + c] = sO[c] - mx - logf(se);
    }
}

extern "C" void kernel_launch(void* const* d_in, const int* in_sizes, int n_in,
                              void* d_out, int out_size, void* d_ws, size_t ws_size,
                              hipStream_t stream) {
    const float* x_in = (const float*)d_in[0];
    const float* adj  = (const float*)d_in[1];
    // d_in[2] = idx (graphs are contiguous 128-node blocks by construction)
    const float* W1 = (const float*)d_in[3];
    const float* b1 = (const float*)d_in[4];
    const float* W2 = (const float*)d_in[5];
    const float* b2 = (const float*)d_in[6];
    const float* Wl = (const float*)d_in[7];
    const float* bl = (const float*)d_in[8];
    float* out = (float*)d_out;

    char* ws = (char*)d_ws;
    float* h1 = (float*)ws;                                   // 2 MB
    float* h2 = h1 + NN * DH;                                 // 2 MB
    u64*   bmp = (u64*)(ws + 8 * 1024 * 1024);                // 8 MB bitmap

    // MEASUREMENT: scan launched twice (idempotent). scan_time = total - 100.3
    scan_bitmap<<<2048, 256, 0, stream>>>(adj, bmp);
    scan_bitmap<<<2048, 256, 0, stream>>>(adj, bmp);
    gin_layer<<<NN / (4 * RPW), 256, 0, stream>>>(x_in, bmp, W1, b1, h1);
    gin_layer<<<NN / (4 * RPW), 256, 0, stream>>>(h1, bmp, W2, b2, h2);
    rspool_head<<<NG, 256, 0, stream>>>(h2, Wl, bl, out);
}

// Round 9
// 96.324 us; speedup vs baseline: 1.5009x; 1.5009x over previous
//
#include <hip/hip_runtime.h>
#include <math.h>

#define NN 8192
#define DH 64
#define DOUT 10
#define NG 64      // number of graphs
#define NPG 128    // nodes per graph
#define NITER 5
#define CAP 192    // max edges per row (deg ~82 +- 9; +5 pad)
#define NCHUNK (NN * NN / 256)   // 262144 chunks of 256 floats
#define RPW 2      // rows per wave in gin_layer

typedef float f32x4 __attribute__((ext_vector_type(4)));
typedef unsigned long long u64;
typedef u64 u64x2 __attribute__((ext_vector_type(2)));

// Grid-stride streaming scan: adj -> occupancy bitmap. MEASURED at 44.3 us
// (round 8 double-launch differencing) = 6.05 TB/s = read roofline. Frozen.
// Bit layout: chunk g, word K (0..3), bit b <-> col g*256 + 4*b + K.
__global__ __launch_bounds__(256) void scan_bitmap(
    const float* __restrict__ adj, u64* __restrict__ bmp)
{
    const int lane = threadIdx.x & 63;
    const int gw   = (blockIdx.x * 256 + threadIdx.x) >> 6;
    const int nw   = (gridDim.x * 256) >> 6;
    #pragma unroll 4
    for (int g = gw; g < NCHUNK; g += nw) {
        f32x4 a4 = *reinterpret_cast<const f32x4*>(adj + (size_t)g * 256 + lane * 4);
        u64 m0 = __ballot(a4.x != 0.0f);
        u64 m1 = __ballot(a4.y != 0.0f);
        u64 m2 = __ballot(a4.z != 0.0f);
        u64 m3 = __ballot(a4.w != 0.0f);
        u64 msel = (lane & 2) ? ((lane & 1) ? m3 : m2)
                              : ((lane & 1) ? m1 : m0);
        if (lane < 4) bmp[(size_t)g * 4 + lane] = msel;
    }
}

// GIN layer from bitmap: one wave per row (RPW rows each).
// Gather: 4 edges per VMEM instruction (float4/lane, 1 KB/wave) ->
// cross-group shfl_xor reduce -> LDS bounce -> linear via 16 uniform
// ds_read_b128 against W column held in 64 VGPRs. ReLU. No barriers in loop.
__global__ __launch_bounds__(256) void gin_layer(
    const float* __restrict__ x, const u64* __restrict__ bmp,
    const float* __restrict__ W, const float* __restrict__ bias,
    float* __restrict__ out)
{
    __shared__ float sW[DH * DH];
    __shared__ unsigned short sJ[4][CAP];
    __shared__ float sAccF[4][DH];

    for (int t = threadIdx.x; t < DH * DH; t += 256) sW[t] = W[t];
    __syncthreads();

    const int wave = threadIdx.x >> 6;
    const int lane = threadIdx.x & 63;
    const int grp  = lane >> 4;          // edge sub-group 0..3
    const int fc   = (lane & 15) * 4;    // feature slice for gather

    float wreg[DH];
    #pragma unroll
    for (int k = 0; k < DH; ++k) wreg[k] = sW[k * DH + lane];  // W column `lane`
    const float bl_ = bias[lane];

    const int wgid = blockIdx.x * 4 + wave;

    for (int rr = 0; rr < RPW; ++rr) {
        const int row = wgid * RPW + rr;
        const u64* brow = bmp + (size_t)row * (NN / 64);   // 128 words

        u64x2 wp = *reinterpret_cast<const u64x2*>(brow + 2 * lane);
        u64 w0 = wp.x, w1 = wp.y;
        int cnt = __popcll(w0) + __popcll(w1);

        int p = cnt;                      // inclusive prefix over lanes
        #pragma unroll
        for (int off = 1; off < 64; off <<= 1) {
            int t = __shfl_up(p, off);
            if (lane >= off) p += t;
        }
        int pos  = p - cnt;               // exclusive prefix
        int ctot = __shfl(p, 63);

        {   // emit edges for my two words (bit b of word widx -> column j)
            int widx = 2 * lane;
            int base0 = (widx >> 2) * 256 + (widx & 3);
            while (w0) { int b = __ffsll(w0) - 1; w0 &= w0 - 1;
                         sJ[wave][pos++] = (unsigned short)(base0 + 4 * b); }
            int widx1 = 2 * lane + 1;
            int base1 = (widx1 >> 2) * 256 + (widx1 & 3);
            while (w1) { int b = __ffsll(w1) - 1; w1 &= w1 - 1;
                         sJ[wave][pos++] = (unsigned short)(base1 + 4 * b); }
        }
        // append self-loop as edge ctot; pad 4 safe slots (masked out below)
        if (lane == 0) sJ[wave][ctot] = (unsigned short)row;
        if (lane < 4)  sJ[wave][ctot + 1 + lane] = 0;
        const int total = ctot + 1;

        // gather: 4 edges per iteration, float4 per lane
        f32x4 acc4 = {0.0f, 0.0f, 0.0f, 0.0f};
        for (int e = 0; e < total; e += 4) {
            int eg = e + grp;
            int j = sJ[wave][eg];                       // padded-safe
            f32x4 v = *reinterpret_cast<const f32x4*>(x + j * DH + fc);
            if (eg < total) acc4 += v;
        }
        // reduce across the 4 edge sub-groups (lanes l, l^16, l^32, l^48)
        #pragma unroll
        for (int c = 0; c < 4; ++c) {
            float a = acc4[c];
            a += __shfl_xor(a, 16);
            a += __shfl_xor(a, 32);
            acc4[c] = a;
        }
        // bounce to per-lane-feature layout (same-wave LDS, ordered)
        if (lane < 16) *reinterpret_cast<f32x4*>(&sAccF[wave][fc]) = acc4;

        float o = bl_;
        #pragma unroll
        for (int q = 0; q < 16; ++q) {
            f32x4 hv = *reinterpret_cast<const f32x4*>(&sAccF[wave][4 * q]);
            o = fmaf(hv.x, wreg[4 * q + 0], o);
            o = fmaf(hv.y, wreg[4 * q + 1], o);
            o = fmaf(hv.z, wreg[4 * q + 2], o);
            o = fmaf(hv.w, wreg[4 * q + 3], o);
        }
        out[row * DH + lane] = fmaxf(o, 0.0f);
    }
}

// One block (256 threads) per graph: power-iteration rs-pool + classifier + log_softmax
__global__ __launch_bounds__(256) void rspool_head(
    const float* __restrict__ h, const float* __restrict__ Wl,
    const float* __restrict__ bl, float* __restrict__ out)
{
    __shared__ float sX[NPG * 65];    // padded LD=65: conflict-free both axes
    __shared__ float sY[NPG];
    __shared__ float sVec[DH];
    __shared__ float sPart[4][DH];
    __shared__ float sPooled[DH];
    __shared__ float sO[DOUT];

    const int g = blockIdx.x;
    const int d = threadIdx.x & 63;
    const int q = threadIdx.x >> 6;

    const float* hg = h + (size_t)g * NPG * DH;
    for (int t = threadIdx.x; t < NPG * DH; t += 256)
        sX[(t >> 6) * 65 + (t & 63)] = hg[t];
    __syncthreads();

    {
        float p = 0.0f;
        for (int i = q * 32; i < q * 32 + 32; ++i) p += sX[i * 65 + d];
        sPart[q][d] = p;
    }
    __syncthreads();
    if (threadIdx.x < 64) {
        float v = sPart[0][d] + sPart[1][d] + sPart[2][d] + sPart[3][d];
        float s = v * v;
        #pragma unroll
        for (int off = 32; off > 0; off >>= 1) s += __shfl_xor(s, off);
        sVec[d] = v / (sqrtf(s) + 1e-8f);
    }
    __syncthreads();

    for (int it = 0; it < NITER; ++it) {
        if (threadIdx.x < NPG) {
            int i = threadIdx.x;
            float yy = 0.0f;
            #pragma unroll
            for (int dd = 0; dd < DH; ++dd) yy += sX[i * 65 + dd] * sVec[dd];
            sY[i] = yy;
        }
        __syncthreads();
        {
            float p = 0.0f;
            for (int i = q * 32; i < q * 32 + 32; ++i) p += sY[i] * sX[i * 65 + d];
            sPart[q][d] = p;
        }
        __syncthreads();
        if (threadIdx.x < 64) {
            float v = sPart[0][d] + sPart[1][d] + sPart[2][d] + sPart[3][d];
            float s = v * v;
            #pragma unroll
            for (int off = 32; off > 0; off >>= 1) s += __shfl_xor(s, off);
            sVec[d] = v / (sqrtf(s) + 1e-8f);
        }
        __syncthreads();
    }

    if (threadIdx.x < NPG) {
        int i = threadIdx.x;
        float yy = 0.0f;
        #pragma unroll
        for (int dd = 0; dd < DH; ++dd) yy += sX[i * 65 + dd] * sVec[dd];
        sY[i] = yy;
    }
    __syncthreads();
    if (threadIdx.x < 64) {
        float s = sY[d] * sY[d] + sY[64 + d] * sY[64 + d];
        #pragma unroll
        for (int off = 32; off > 0; off >>= 1) s += __shfl_xor(s, off);
        float sv = sqrtf(s);
        sPooled[d] = sVec[d] * sv;
    }
    __syncthreads();

    if (threadIdx.x < DOUT) {
        int c = threadIdx.x;
        float o = bl[c];
        #pragma unroll
        for (int dd = 0; dd < DH; ++dd) o += sPooled[dd] * Wl[dd * DOUT + c];
        sO[c] = o;
    }
    __syncthreads();
    if (threadIdx.x < DOUT) {
        int c = threadIdx.x;
        float mx = -INFINITY;
        #pragma unroll
        for (int j = 0; j < DOUT; ++j) mx = fmaxf(mx, sO[j]);
        float se = 0.0f;
        #pragma unroll
        for (int j = 0; j < DOUT; ++j) se += expf(sO[j] - mx);
        out[g * DOUT + c] = sO[c] - mx - logf(se);
    }
}

extern "C" void kernel_launch(void* const* d_in, const int* in_sizes, int n_in,
                              void* d_out, int out_size, void* d_ws, size_t ws_size,
                              hipStream_t stream) {
    const float* x_in = (const float*)d_in[0];
    const float* adj  = (const float*)d_in[1];
    // d_in[2] = idx (graphs are contiguous 128-node blocks by construction)
    const float* W1 = (const float*)d_in[3];
    const float* b1 = (const float*)d_in[4];
    const float* W2 = (const float*)d_in[5];
    const float* b2 = (const float*)d_in[6];
    const float* Wl = (const float*)d_in[7];
    const float* bl = (const float*)d_in[8];
    float* out = (float*)d_out;

    char* ws = (char*)d_ws;
    float* h1 = (float*)ws;                                   // 2 MB
    float* h2 = h1 + NN * DH;                                 // 2 MB
    u64*   bmp = (u64*)(ws + 8 * 1024 * 1024);                // 8 MB bitmap

    scan_bitmap<<<2048, 256, 0, stream>>>(adj, bmp);
    gin_layer<<<NN / (4 * RPW), 256, 0, stream>>>(x_in, bmp, W1, b1, h1);
    gin_layer<<<NN / (4 * RPW), 256, 0, stream>>>(h1, bmp, W2, b2, h2);
    rspool_head<<<NG, 256, 0, stream>>>(h2, Wl, bl, out);
}

// Round 10
// 89.010 us; speedup vs baseline: 1.6242x; 1.0822x over previous
//
#include <hip/hip_runtime.h>
#include <math.h>

#define NN 8192
#define DH 64
#define DOUT 10
#define NG 64      // number of graphs
#define NPG 128    // nodes per graph
#define NITER 5
#define TPAD 160   // fixed padded edge-list length (max deg ~120 @8.7 sigma)
#define NCHUNK (NN * NN / 256)   // 262144 chunks of 256 floats

typedef float f32x4 __attribute__((ext_vector_type(4)));
typedef unsigned long long u64;
typedef u64 u64x2 __attribute__((ext_vector_type(2)));

// Grid-stride streaming scan: adj -> occupancy bitmap. MEASURED at 44.3 us
// (round 8 double-launch differencing) = 6.05 TB/s = read roofline. Frozen.
// Bit layout: chunk g, word K (0..3), bit b <-> col g*256 + 4*b + K.
__global__ __launch_bounds__(256) void scan_bitmap(
    const float* __restrict__ adj, u64* __restrict__ bmp)
{
    const int lane = threadIdx.x & 63;
    const int gw   = (blockIdx.x * 256 + threadIdx.x) >> 6;
    const int nw   = (gridDim.x * 256) >> 6;
    #pragma unroll 4
    for (int g = gw; g < NCHUNK; g += nw) {
        f32x4 a4 = *reinterpret_cast<const f32x4*>(adj + (size_t)g * 256 + lane * 4);
        u64 m0 = __ballot(a4.x != 0.0f);
        u64 m1 = __ballot(a4.y != 0.0f);
        u64 m2 = __ballot(a4.z != 0.0f);
        u64 m3 = __ballot(a4.w != 0.0f);
        u64 msel = (lane & 2) ? ((lane & 1) ? m3 : m2)
                              : ((lane & 1) ? m1 : m0);
        if (lane < 4) bmp[(size_t)g * 4 + lane] = msel;
    }
}

// GIN layer from bitmap: ONE ROW PER WAVE, 4 waves/block, 2048 blocks
// (8 waves/SIMD for latency hiding). Gather uses a 16-deep explicit batch
// pipeline (16 independent coalesced loads in flight); adds stay in strict
// emission order with self-loop FIRST -> bit-exact vs rounds 1-8.
// Linear reads both operands from LDS (uniform + stride-1, conflict-free);
// no 64-VGPR W column -> VGPR ~60 -> full occupancy.
__global__ __launch_bounds__(256) void gin_layer(
    const float* __restrict__ x, const u64* __restrict__ bmp,
    const float* __restrict__ W, const float* __restrict__ bias,
    float* __restrict__ out)
{
    __shared__ float sW[DH * DH];              // 16 KB
    __shared__ unsigned short sJ[4][TPAD];     // 1.25 KB
    __shared__ float sAccF[4][DH];             // 1 KB

    for (int t = threadIdx.x; t < DH * DH; t += 256) sW[t] = W[t];
    __syncthreads();

    const int wave = threadIdx.x >> 6;
    const int lane = threadIdx.x & 63;
    const int row  = blockIdx.x * 4 + wave;

    // ---- extract edges from bitmap (as rounds 6-8: lane-major emission) ----
    const u64* brow = bmp + (size_t)row * (NN / 64);   // 128 words
    u64x2 wp = *reinterpret_cast<const u64x2*>(brow + 2 * lane);
    u64 w0 = wp.x, w1 = wp.y;
    int cnt = __popcll(w0) + __popcll(w1);

    int p = cnt;                      // inclusive prefix over lanes
    #pragma unroll
    for (int off = 1; off < 64; off <<= 1) {
        int t = __shfl_up(p, off);
        if (lane >= off) p += t;
    }
    int pos  = p - cnt;               // exclusive prefix
    int ctot = __shfl(p, 63);

    {   // emit edges for my two words (bit b of word widx -> column j)
        int widx = 2 * lane;
        int base0 = (widx >> 2) * 256 + (widx & 3);
        while (w0) { int b = __ffsll(w0) - 1; w0 &= w0 - 1;
                     sJ[wave][pos++] = (unsigned short)(base0 + 4 * b); }
        int widx1 = 2 * lane + 1;
        int base1 = (widx1 >> 2) * 256 + (widx1 & 3);
        while (w1) { int b = __ffsll(w1) - 1; w1 &= w1 - 1;
                     sJ[wave][pos++] = (unsigned short)(base1 + 4 * b); }
    }
    // pad to TPAD with index 0 (loads are L1-hot, adds are masked to +0.0)
    for (int e = ctot + lane; e < TPAD; e += 64) sJ[wave][e] = 0;

    // ---- gather: 16-deep batch pipeline, adds in strict e-order ----
    float acc = x[row * DH + lane];            // self-loop FIRST (bit-exact)
    const int tmax = (ctot + 15) & ~15;
    #pragma unroll 1
    for (int e0 = 0; e0 < tmax; e0 += 16) {
        int jj[16];
        float vv[16];
        #pragma unroll
        for (int s = 0; s < 16; ++s) jj[s] = sJ[wave][e0 + s];   // uniform bcast
        #pragma unroll
        for (int s = 0; s < 16; ++s) vv[s] = x[jj[s] * DH + lane]; // independent
        #pragma unroll
        for (int s = 0; s < 16; ++s)
            acc += (e0 + s < ctot) ? vv[s] : 0.0f;               // ordered adds
    }

    // ---- linear + ReLU from LDS (uniform x stride-1, conflict-free) ----
    sAccF[wave][lane] = acc;
    float o = bias[lane];
    #pragma unroll
    for (int k = 0; k < DH; ++k) o += sAccF[wave][k] * sW[k * DH + lane];
    out[row * DH + lane] = fmaxf(o, 0.0f);
}

// One block (256 threads) per graph: power-iteration rs-pool + classifier + log_softmax
__global__ __launch_bounds__(256) void rspool_head(
    const float* __restrict__ h, const float* __restrict__ Wl,
    const float* __restrict__ bl, float* __restrict__ out)
{
    __shared__ float sX[NPG * 65];    // padded LD=65: conflict-free both axes
    __shared__ float sY[NPG];
    __shared__ float sVec[DH];
    __shared__ float sPart[4][DH];
    __shared__ float sPooled[DH];
    __shared__ float sO[DOUT];

    const int g = blockIdx.x;
    const int d = threadIdx.x & 63;
    const int q = threadIdx.x >> 6;

    const float* hg = h + (size_t)g * NPG * DH;
    for (int t = threadIdx.x; t < NPG * DH; t += 256)
        sX[(t >> 6) * 65 + (t & 63)] = hg[t];
    __syncthreads();

    {
        float p = 0.0f;
        for (int i = q * 32; i < q * 32 + 32; ++i) p += sX[i * 65 + d];
        sPart[q][d] = p;
    }
    __syncthreads();
    if (threadIdx.x < 64) {
        float v = sPart[0][d] + sPart[1][d] + sPart[2][d] + sPart[3][d];
        float s = v * v;
        #pragma unroll
        for (int off = 32; off > 0; off >>= 1) s += __shfl_xor(s, off);
        sVec[d] = v / (sqrtf(s) + 1e-8f);
    }
    __syncthreads();

    for (int it = 0; it < NITER; ++it) {
        if (threadIdx.x < NPG) {
            int i = threadIdx.x;
            float yy = 0.0f;
            #pragma unroll
            for (int dd = 0; dd < DH; ++dd) yy += sX[i * 65 + dd] * sVec[dd];
            sY[i] = yy;
        }
        __syncthreads();
        {
            float p = 0.0f;
            for (int i = q * 32; i < q * 32 + 32; ++i) p += sY[i] * sX[i * 65 + d];
            sPart[q][d] = p;
        }
        __syncthreads();
        if (threadIdx.x < 64) {
            float v = sPart[0][d] + sPart[1][d] + sPart[2][d] + sPart[3][d];
            float s = v * v;
            #pragma unroll
            for (int off = 32; off > 0; off >>= 1) s += __shfl_xor(s, off);
            sVec[d] = v / (sqrtf(s) + 1e-8f);
        }
        __syncthreads();
    }

    if (threadIdx.x < NPG) {
        int i = threadIdx.x;
        float yy = 0.0f;
        #pragma unroll
        for (int dd = 0; dd < DH; ++dd) yy += sX[i * 65 + dd] * sVec[dd];
        sY[i] = yy;
    }
    __syncthreads();
    if (threadIdx.x < 64) {
        float s = sY[d] * sY[d] + sY[64 + d] * sY[64 + d];
        #pragma unroll
        for (int off = 32; off > 0; off >>= 1) s += __shfl_xor(s, off);
        float sv = sqrtf(s);
        sPooled[d] = sVec[d] * sv;
    }
    __syncthreads();

    if (threadIdx.x < DOUT) {
        int c = threadIdx.x;
        float o = bl[c];
        #pragma unroll
        for (int dd = 0; dd < DH; ++dd) o += sPooled[dd] * Wl[dd * DOUT + c];
        sO[c] = o;
    }
    __syncthreads();
    if (threadIdx.x < DOUT) {
        int c = threadIdx.x;
        float mx = -INFINITY;
        #pragma unroll
        for (int j = 0; j < DOUT; ++j) mx = fmaxf(mx, sO[j]);
        float se = 0.0f;
        #pragma unroll
        for (int j = 0; j < DOUT; ++j) se += expf(sO[j] - mx);
        out[g * DOUT + c] = sO[c] - mx - logf(se);
    }
}

extern "C" void kernel_launch(void* const* d_in, const int* in_sizes, int n_in,
                              void* d_out, int out_size, void* d_ws, size_t ws_size,
                              hipStream_t stream) {
    const float* x_in = (const float*)d_in[0];
    const float* adj  = (const float*)d_in[1];
    // d_in[2] = idx (graphs are contiguous 128-node blocks by construction)
    const float* W1 = (const float*)d_in[3];
    const float* b1 = (const float*)d_in[4];
    const float* W2 = (const float*)d_in[5];
    const float* b2 = (const float*)d_in[6];
    const float* Wl = (const float*)d_in[7];
    const float* bl = (const float*)d_in[8];
    float* out = (float*)d_out;

    char* ws = (char*)d_ws;
    float* h1 = (float*)ws;                                   // 2 MB
    float* h2 = h1 + NN * DH;                                 // 2 MB
    u64*   bmp = (u64*)(ws + 8 * 1024 * 1024);                // 8 MB bitmap

    scan_bitmap<<<2048, 256, 0, stream>>>(adj, bmp);
    gin_layer<<<NN / 4, 256, 0, stream>>>(x_in, bmp, W1, b1, h1);
    gin_layer<<<NN / 4, 256, 0, stream>>>(h1, bmp, W2, b2, h2);
    rspool_head<<<NG, 256, 0, stream>>>(h2, Wl, bl, out);
}

// Round 11
// 87.559 us; speedup vs baseline: 1.6512x; 1.0166x over previous
//
#include <hip/hip_runtime.h>
#include <math.h>

#define NN 8192
#define DH 64
#define DOUT 10
#define NG 64      // number of graphs
#define NPG 128    // nodes per graph
#define NITER 5
#define TPAD 160   // fixed padded edge-list length (max deg ~120 @8.7 sigma)
#define NCHUNK (NN * NN / 256)   // 262144 chunks of 256 floats

typedef float f32x4 __attribute__((ext_vector_type(4)));
typedef unsigned long long u64;
typedef u64 u64x2 __attribute__((ext_vector_type(2)));

// Grid-stride streaming scan: adj -> occupancy bitmap. MEASURED at 44.3 us
// (round 8 double-launch differencing) = 6.05 TB/s = read roofline. Frozen.
// Bit layout: chunk g, word K (0..3), bit b <-> col g*256 + 4*b + K.
__global__ __launch_bounds__(256) void scan_bitmap(
    const float* __restrict__ adj, u64* __restrict__ bmp)
{
    const int lane = threadIdx.x & 63;
    const int gw   = (blockIdx.x * 256 + threadIdx.x) >> 6;
    const int nw   = (gridDim.x * 256) >> 6;
    #pragma unroll 4
    for (int g = gw; g < NCHUNK; g += nw) {
        f32x4 a4 = *reinterpret_cast<const f32x4*>(adj + (size_t)g * 256 + lane * 4);
        u64 m0 = __ballot(a4.x != 0.0f);
        u64 m1 = __ballot(a4.y != 0.0f);
        u64 m2 = __ballot(a4.z != 0.0f);
        u64 m3 = __ballot(a4.w != 0.0f);
        u64 msel = (lane & 2) ? ((lane & 1) ? m3 : m2)
                              : ((lane & 1) ? m1 : m0);
        if (lane < 4) bmp[(size_t)g * 4 + lane] = msel;
    }
}

// GIN layer from bitmap: ONE ROW PER WAVE, 4 waves/block, 2048 blocks.
// Round 11: LDS-op diet. Same VALUES and ADD/FMA ORDER as round 10
// (absmax 0.0) — only the transport of uniform scalars changed:
//  - 16 edge indices per batch via 2 uniform ds_read_b128 (was 16 ds_read_u16)
//  - acc broadcast via v_readlane (SALU) instead of 64 uniform LDS reads
//  - W reads unchanged (64 conflict-free ds_read_b32)
__global__ __launch_bounds__(256) void gin_layer(
    const float* __restrict__ x, const u64* __restrict__ bmp,
    const float* __restrict__ W, const float* __restrict__ bias,
    float* __restrict__ out)
{
    __shared__ float sW[DH * DH];              // 16 KB
    __shared__ unsigned short sJ[4][TPAD];     // 1.25 KB

    for (int t = threadIdx.x; t < DH * DH; t += 256) sW[t] = W[t];
    __syncthreads();

    const int wave = threadIdx.x >> 6;
    const int lane = threadIdx.x & 63;
    const int row  = blockIdx.x * 4 + wave;

    // ---- extract edges from bitmap (identical to round 10) ----
    const u64* brow = bmp + (size_t)row * (NN / 64);   // 128 words
    u64x2 wp = *reinterpret_cast<const u64x2*>(brow + 2 * lane);
    u64 w0 = wp.x, w1 = wp.y;
    int cnt = __popcll(w0) + __popcll(w1);

    int p = cnt;                      // inclusive prefix over lanes
    #pragma unroll
    for (int off = 1; off < 64; off <<= 1) {
        int t = __shfl_up(p, off);
        if (lane >= off) p += t;
    }
    int pos  = p - cnt;               // exclusive prefix
    int ctot = __shfl(p, 63);

    {   // emit edges for my two words (bit b of word widx -> column j)
        int widx = 2 * lane;
        int base0 = (widx >> 2) * 256 + (widx & 3);
        while (w0) { int b = __ffsll(w0) - 1; w0 &= w0 - 1;
                     sJ[wave][pos++] = (unsigned short)(base0 + 4 * b); }
        int widx1 = 2 * lane + 1;
        int base1 = (widx1 >> 2) * 256 + (widx1 & 3);
        while (w1) { int b = __ffsll(w1) - 1; w1 &= w1 - 1;
                     sJ[wave][pos++] = (unsigned short)(base1 + 4 * b); }
    }
    // pad to TPAD with index 0 (loads are L1-hot, adds are masked to +0.0)
    for (int e = ctot + lane; e < TPAD; e += 64) sJ[wave][e] = 0;

    // ---- gather: 16-deep batch pipeline, adds in strict e-order ----
    float acc = x[row * DH + lane];            // self-loop FIRST (bit-exact)
    const int tmax = (ctot + 15) & ~15;
    #pragma unroll 1
    for (int e0 = 0; e0 < tmax; e0 += 16) {
        const uint4* sj4 = reinterpret_cast<const uint4*>(&sJ[wave][e0]);
        uint4 ja = sj4[0];                     // uniform b128 broadcast
        uint4 jb = sj4[1];
        unsigned jj[16];
        jj[ 0] = ja.x & 0xffffu; jj[ 1] = ja.x >> 16;
        jj[ 2] = ja.y & 0xffffu; jj[ 3] = ja.y >> 16;
        jj[ 4] = ja.z & 0xffffu; jj[ 5] = ja.z >> 16;
        jj[ 6] = ja.w & 0xffffu; jj[ 7] = ja.w >> 16;
        jj[ 8] = jb.x & 0xffffu; jj[ 9] = jb.x >> 16;
        jj[10] = jb.y & 0xffffu; jj[11] = jb.y >> 16;
        jj[12] = jb.z & 0xffffu; jj[13] = jb.z >> 16;
        jj[14] = jb.w & 0xffffu; jj[15] = jb.w >> 16;
        float vv[16];
        #pragma unroll
        for (int s = 0; s < 16; ++s) vv[s] = x[jj[s] * DH + lane]; // independent
        #pragma unroll
        for (int s = 0; s < 16; ++s)
            acc += (e0 + s < ctot) ? vv[s] : 0.0f;               // ordered adds
    }

    // ---- linear + ReLU: readlane (SALU) x LDS W, serial k-ascending chain ----
    float o = bias[lane];
    #pragma unroll
    for (int k = 0; k < DH; ++k) {
        float ak = __int_as_float(
            __builtin_amdgcn_readlane(__float_as_int(acc), k));
        o = fmaf(ak, sW[k * DH + lane], o);
    }
    out[row * DH + lane] = fmaxf(o, 0.0f);
}

// One block (256 threads) per graph: power-iteration rs-pool + classifier + log_softmax
__global__ __launch_bounds__(256) void rspool_head(
    const float* __restrict__ h, const float* __restrict__ Wl,
    const float* __restrict__ bl, float* __restrict__ out)
{
    __shared__ float sX[NPG * 65];    // padded LD=65: conflict-free both axes
    __shared__ float sY[NPG];
    __shared__ float sVec[DH];
    __shared__ float sPart[4][DH];
    __shared__ float sPooled[DH];
    __shared__ float sO[DOUT];

    const int g = blockIdx.x;
    const int d = threadIdx.x & 63;
    const int q = threadIdx.x >> 6;

    const float* hg = h + (size_t)g * NPG * DH;
    for (int t = threadIdx.x; t < NPG * DH; t += 256)
        sX[(t >> 6) * 65 + (t & 63)] = hg[t];
    __syncthreads();

    {
        float p = 0.0f;
        for (int i = q * 32; i < q * 32 + 32; ++i) p += sX[i * 65 + d];
        sPart[q][d] = p;
    }
    __syncthreads();
    if (threadIdx.x < 64) {
        float v = sPart[0][d] + sPart[1][d] + sPart[2][d] + sPart[3][d];
        float s = v * v;
        #pragma unroll
        for (int off = 32; off > 0; off >>= 1) s += __shfl_xor(s, off);
        sVec[d] = v / (sqrtf(s) + 1e-8f);
    }
    __syncthreads();

    for (int it = 0; it < NITER; ++it) {
        if (threadIdx.x < NPG) {
            int i = threadIdx.x;
            float yy = 0.0f;
            #pragma unroll
            for (int dd = 0; dd < DH; ++dd) yy += sX[i * 65 + dd] * sVec[dd];
            sY[i] = yy;
        }
        __syncthreads();
        {
            float p = 0.0f;
            for (int i = q * 32; i < q * 32 + 32; ++i) p += sY[i] * sX[i * 65 + d];
            sPart[q][d] = p;
        }
        __syncthreads();
        if (threadIdx.x < 64) {
            float v = sPart[0][d] + sPart[1][d] + sPart[2][d] + sPart[3][d];
            float s = v * v;
            #pragma unroll
            for (int off = 32; off > 0; off >>= 1) s += __shfl_xor(s, off);
            sVec[d] = v / (sqrtf(s) + 1e-8f);
        }
        __syncthreads();
    }

    if (threadIdx.x < NPG) {
        int i = threadIdx.x;
        float yy = 0.0f;
        #pragma unroll
        for (int dd = 0; dd < DH; ++dd) yy += sX[i * 65 + dd] * sVec[dd];
        sY[i] = yy;
    }
    __syncthreads();
    if (threadIdx.x < 64) {
        float s = sY[d] * sY[d] + sY[64 + d] * sY[64 + d];
        #pragma unroll
        for (int off = 32; off > 0; off >>= 1) s += __shfl_xor(s, off);
        float sv = sqrtf(s);
        sPooled[d] = sVec[d] * sv;
    }
    __syncthreads();

    if (threadIdx.x < DOUT) {
        int c = threadIdx.x;
        float o = bl[c];
        #pragma unroll
        for (int dd = 0; dd < DH; ++dd) o += sPooled[dd] * Wl[dd * DOUT + c];
        sO[c] = o;
    }
    __syncthreads();
    if (threadIdx.x < DOUT) {
        int c = threadIdx.x;
        float mx = -INFINITY;
        #pragma unroll
        for (int j = 0; j < DOUT; ++j) mx = fmaxf(mx, sO[j]);
        float se = 0.0f;
        #pragma unroll
        for (int j = 0; j < DOUT; ++j) se += expf(sO[j] - mx);
        out[g * DOUT + c] = sO[c] - mx - logf(se);
    }
}

extern "C" void kernel_launch(void* const* d_in, const int* in_sizes, int n_in,
                              void* d_out, int out_size, void* d_ws, size_t ws_size,
                              hipStream_t stream) {
    const float* x_in = (const float*)d_in[0];
    const float* adj  = (const float*)d_in[1];
    // d_in[2] = idx (graphs are contiguous 128-node blocks by construction)
    const float* W1 = (const float*)d_in[3];
    const float* b1 = (const float*)d_in[4];
    const float* W2 = (const float*)d_in[5];
    const float* b2 = (const float*)d_in[6];
    const float* Wl = (const float*)d_in[7];
    const float* bl = (const float*)d_in[8];
    float* out = (float*)d_out;

    char* ws = (char*)d_ws;
    float* h1 = (float*)ws;                                   // 2 MB
    float* h2 = h1 + NN * DH;                                 // 2 MB
    u64*   bmp = (u64*)(ws + 8 * 1024 * 1024);                // 8 MB bitmap

    scan_bitmap<<<2048, 256, 0, stream>>>(adj, bmp);
    gin_layer<<<NN / 4, 256, 0, stream>>>(x_in, bmp, W1, b1, h1);
    gin_layer<<<NN / 4, 256, 0, stream>>>(h1, bmp, W2, b2, h2);
    rspool_head<<<NG, 256, 0, stream>>>(h2, Wl, bl, out);
}